// Round 8
// baseline (1144.917 us; speedup 1.0000x reference)
//
#include <hip/hip_runtime.h>
#include <math.h>

// Transformer decoder forward. Round 8: attention K/V register double-buffer
// prefetch (T14 async-stage) — tile t+1's 16 global loads issue before tile
// t's compute, hiding L2 latency under MFMA+exp. Numerics identical to r7.
// GEMM/LN/embed identical to round 5 (proven).

#define TB   4
#define TS   1024
#define TD   512
#define TH   8
#define TDK  64
#define TDFF 2048
#define TNL  4
#define MASKV -2147483648.0f

typedef __attribute__((ext_vector_type(8))) short short8;
typedef __attribute__((ext_vector_type(4))) float f32x4;

__device__ __forceinline__ float wave_sum(float v) {
#pragma unroll
  for (int off = 32; off > 0; off >>= 1) v += __shfl_xor(v, off, 64);
  return v;
}

__device__ __forceinline__ ushort f2bf(float f) {  // RNE fp32 -> bf16 bits
  unsigned u = __float_as_uint(f);
  return (ushort)((u + 0x7FFFu + ((u >> 16) & 1u)) >> 16);
}

__device__ __forceinline__ void gload16(const ushort* g, ushort* l) {
  __builtin_amdgcn_global_load_lds(
      (const __attribute__((address_space(1))) void*)g,
      (__attribute__((address_space(3))) void*)l, 16, 0, 0);
}

// ---------------------------------------------------------------- embeddings
__global__ __launch_bounds__(256) void embed_k(
    const float* __restrict__ inp, const float* __restrict__ outp,
    const float* __restrict__ eiw, const float* __restrict__ eib,
    const float* __restrict__ eow, const float* __restrict__ eob,
    ushort* __restrict__ ench, float* __restrict__ dec,
    ushort* __restrict__ dech) {
  int idx = blockIdx.x * 256 + threadIdx.x;   // over S*D
  int s = idx >> 9, d = idx & 511;
  int i2 = d & ~1;
  float expo = (float)i2 * (1.0f / 512.0f);
  float denom = powf(10000.0f, expo);
  float theta = (float)s / denom;
  float pe = (d & 1) ? cosf(theta) : sinf(theta);
  float wi = eiw[d], bi = eib[d], wo = eow[d], bo = eob[d];
#pragma unroll
  for (int b = 0; b < TB; ++b) {
    float vi = inp[b * TS + s], vo = outp[b * TS + s];
    size_t o = ((size_t)(b * TS + s)) * TD + d;
    float ev = vi * wi + bi + pe;
    float dv = vo * wo + bo + pe;
    ench[o] = f2bf(ev);
    dec[o] = dv;
    dech[o] = f2bf(dv);
  }
}

// ---------------------------------------------------------------- weight prep
__global__ __launch_bounds__(256) void tcast_k(
    const float* p0, const float* p1, const float* p2, const float* p3,
    const float* p4, const float* p5, const float* p6, const float* p7,
    const float* pf1, const float* pf2, ushort* __restrict__ Wt) {
  __shared__ float s[32][33];
  const float* pp[8] = {p0, p1, p2, p3, p4, p5, p6, p7};
  int t = blockIdx.x;
  const float* src;
  ushort* dst;
  int K, N, kt, nt;
  if (t < 2048) {
    int m = t >> 8, w = t & 255;
    K = 512; N = 512; kt = w & 15; nt = w >> 4;
    src = pp[m]; dst = Wt + (size_t)m * 262144;
  } else if (t < 3072) {
    int w = t - 2048;
    K = 512; N = 2048; kt = w & 15; nt = w >> 4;
    src = pf1; dst = Wt + 2097152;
  } else {
    int w = t - 3072;
    K = 2048; N = 512; kt = w >> 4; nt = w & 15;
    src = pf2; dst = Wt + 3145728;
  }
  int tx = threadIdx.x & 31, ty = threadIdx.x >> 5;
  int k0 = kt << 5, n0 = nt << 5;
#pragma unroll
  for (int it = 0; it < 4; ++it) {
    int r = ty + (it << 3);
    s[r][tx] = src[(size_t)(k0 + r) * N + n0 + tx];
  }
  __syncthreads();
#pragma unroll
  for (int it = 0; it < 4; ++it) {
    int r = ty + (it << 3);
    dst[(size_t)(n0 + r) * K + k0 + tx] = f2bf(s[tx][r]);
  }
}

// ---------------------------------------------------------------- bf16 GEMM
// (unchanged from round 5 — proven)
template <int OUT, int ASPLIT>
__global__ __launch_bounds__(256) void bgemm_k(
    const ushort* __restrict__ A, const ushort* __restrict__ Aalt,
    const ushort* __restrict__ Wt,
    const float* __restrict__ b0, const float* __restrict__ b1,
    const float* __restrict__ b2,
    float* __restrict__ Cf, ushort* __restrict__ C0,
    ushort* __restrict__ C1, ushort* __restrict__ C2,
    int N, int K, int lda, int ldb, int kSplit) {
  __shared__ ushort Ab[2][4096];
  __shared__ ushort Bb[2][4096];
  const int tid = threadIdx.x;
  const int w = tid >> 6, l = tid & 63;
  const int m0 = blockIdx.y * 64, n0 = blockIdx.x * 64;
  const ushort* Abase = (ASPLIT == 1 && n0 >= 512) ? Aalt : A;
  const int srow = w * 8 + (l >> 3);
  const int schunk = l & 7;
  const int r15 = l & 15, kg = l >> 4;
  const int mh = w >> 1, nh = w & 1;
  const int swz = r15 & 7;
  const int ch0 = ((kg ^ swz) << 3);
  const int ch1 = (((kg + 4) ^ swz) << 3);
  const int aoff0 = (mh * 32 + r15) * 64, aoff1 = aoff0 + 16 * 64;
  const int boff0 = (nh * 32 + r15) * 64, boff1 = boff0 + 16 * 64;
  f32x4 z = {0.f, 0.f, 0.f, 0.f};
  f32x4 acc[2][2] = {{z, z}, {z, z}};
  const int nk = K >> 6;

#define STAGE(buf, kbase)                                                    \
  {                                                                          \
    const int kk_ = (kbase);                                                 \
    const ushort* As_ =                                                      \
        (ASPLIT == 2 && kk_ >= kSplit) ? Aalt : Abase;                       \
    const int ka_ = (ASPLIT == 2 && kk_ >= kSplit) ? kk_ - kSplit : kk_;     \
    _Pragma("unroll") for (int rr = 0; rr < 2; ++rr) {                       \
      const int row_ = rr * 32 + srow;                                       \
      const int gch_ = schunk ^ (row_ & 7);                                  \
      gload16(As_ + (size_t)(m0 + row_) * lda + ka_ + gch_ * 8,              \
              &Ab[buf][rr * 2048 + w * 512]);                                \
      gload16(Wt + (size_t)(n0 + row_) * ldb + kk_ + gch_ * 8,               \
              &Bb[buf][rr * 2048 + w * 512]);                                \
    }                                                                        \
  }

  STAGE(0, 0)
  int cur = 0;
  for (int kt = 0; kt < nk; ++kt) {
    __syncthreads();
    if (kt + 1 < nk) STAGE(cur ^ 1, (kt + 1) << 6)
    short8 a0c0 = *(const short8*)&Ab[cur][aoff0 + ch0];
    short8 a1c0 = *(const short8*)&Ab[cur][aoff1 + ch0];
    short8 b0c0 = *(const short8*)&Bb[cur][boff0 + ch0];
    short8 b1c0 = *(const short8*)&Bb[cur][boff1 + ch0];
    acc[0][0] = __builtin_amdgcn_mfma_f32_16x16x32_bf16(a0c0, b0c0, acc[0][0], 0, 0, 0);
    acc[0][1] = __builtin_amdgcn_mfma_f32_16x16x32_bf16(a0c0, b1c0, acc[0][1], 0, 0, 0);
    acc[1][0] = __builtin_amdgcn_mfma_f32_16x16x32_bf16(a1c0, b0c0, acc[1][0], 0, 0, 0);
    acc[1][1] = __builtin_amdgcn_mfma_f32_16x16x32_bf16(a1c0, b1c0, acc[1][1], 0, 0, 0);
    short8 a0c1 = *(const short8*)&Ab[cur][aoff0 + ch1];
    short8 a1c1 = *(const short8*)&Ab[cur][aoff1 + ch1];
    short8 b0c1 = *(const short8*)&Bb[cur][boff0 + ch1];
    short8 b1c1 = *(const short8*)&Bb[cur][boff1 + ch1];
    acc[0][0] = __builtin_amdgcn_mfma_f32_16x16x32_bf16(a0c1, b0c1, acc[0][0], 0, 0, 0);
    acc[0][1] = __builtin_amdgcn_mfma_f32_16x16x32_bf16(a0c1, b1c1, acc[0][1], 0, 0, 0);
    acc[1][0] = __builtin_amdgcn_mfma_f32_16x16x32_bf16(a1c1, b0c1, acc[1][0], 0, 0, 0);
    acc[1][1] = __builtin_amdgcn_mfma_f32_16x16x32_bf16(a1c1, b1c1, acc[1][1], 0, 0, 0);
    cur ^= 1;
  }
#undef STAGE

  const int orow = kg << 2;
  (void)b1; (void)b2; (void)Cf; (void)C0; (void)C1; (void)C2;
#pragma unroll
  for (int rb = 0; rb < 2; ++rb) {
#pragma unroll
    for (int cb = 0; cb < 2; ++cb) {
      const int ncol = n0 + nh * 32 + cb * 16 + r15;
      const int mrb = m0 + mh * 32 + rb * 16 + orow;
      if (OUT == 0) {
        const float bv = b0[ncol];
#pragma unroll
        for (int i = 0; i < 4; ++i)
          Cf[(size_t)(mrb + i) * N + ncol] = acc[rb][cb][i] + bv;
      } else if (OUT == 5) {
        const int seg = n0 >> 9;
        const float* bp = (seg == 0) ? b0 : (seg == 1 ? b1 : b2);
        const float bv = bp[ncol & 511];
        if (seg < 2) {
          ushort* Cp = (seg == 0) ? C0 : C1;
#pragma unroll
          for (int i = 0; i < 4; ++i)
            Cp[(size_t)(mrb + i) * 512 + (ncol & 511)] = f2bf(acc[rb][cb][i] + bv);
        } else {
          const int vcol = ncol & 511;
          size_t base = ((size_t)((mrb >> 10) * 512 + vcol)) * 1024 + (mrb & 1023);
          ushort4 t;
          t.x = f2bf(acc[rb][cb][0] + bv); t.y = f2bf(acc[rb][cb][1] + bv);
          t.z = f2bf(acc[rb][cb][2] + bv); t.w = f2bf(acc[rb][cb][3] + bv);
          *(ushort4*)(C2 + base) = t;
        }
      } else {
        const float bv = b0[ncol];
        ushort* Cp = (ncol < 1024) ? C0 : C1;
        const int cc = ncol & 1023;
#pragma unroll
        for (int i = 0; i < 4; ++i)
          Cp[(size_t)(mrb + i) * 1024 + cc] = f2bf(fmaxf(acc[rb][cb][i] + bv, 0.f));
      }
    }
  }
}

// ---------------------------------------------------------------- MFMA attention
// Round 8: K/V register double-buffer. Buffers are fixed arrays indexed only
// by literal constants (SROA-safe); even/odd unrolled loop alternates A/B.
// Last iteration prefetches tile nkt-1 redundantly (harmless L2 hit).
template <bool CAUSAL>
__global__ __launch_bounds__(256) void mattn_k(
    const ushort* __restrict__ Qh, const ushort* __restrict__ Kh,
    const ushort* __restrict__ Vt, ushort* __restrict__ O) {
  __shared__ ushort P_lds[4][16][72];
  const int tid = threadIdx.x;
  const int w = tid >> 6, lane = tid & 63;
  const int bx = blockIdx.x;
  const int qt = CAUSAL ? ((bx & 1) ? (15 - (bx >> 1)) : (bx >> 1)) : bx;
  const int bh = blockIdx.y;
  const int b = bh >> 3, h = bh & 7;
  const int q0 = qt << 6;
  const int r15 = lane & 15, kg = lane >> 4;
  const ushort* Qp = Qh + ((size_t)(b * TS + q0 + w * 16 + r15)) * TD + h * TDK + kg * 8;
  const short8 qf0 = *(const short8*)(Qp);
  const short8 qf1 = *(const short8*)(Qp + 32);
  const ushort* Kb = Kh + ((size_t)b * TS) * TD + h * TDK + kg * 8 + (size_t)r15 * TD;
  const ushort* Vb = Vt + ((size_t)(b * 512 + h * TDK)) * 1024 + kg * 8 + (size_t)r15 * 1024;
  float lrow[4] = {0.f, 0.f, 0.f, 0.f};
  f32x4 z = {0.f, 0.f, 0.f, 0.f};
  f32x4 o0 = z, o1 = z, o2 = z, o3 = z;
  const int nkt = CAUSAL ? (qt + 1) : (TS / 64);

  short8 kA[8], vA[8], kB[8], vB[8];

#define LOADKV(kt_, KD, VD)                                       \
  {                                                               \
    const ushort* Kp_ = Kb + (((size_t)(kt_)) << 6) * TD;         \
    const ushort* Vp_ = Vb + (((size_t)(kt_)) << 6);              \
    KD[0] = *(const short8*)(Kp_);                                \
    KD[1] = *(const short8*)(Kp_ + 32);                           \
    KD[2] = *(const short8*)(Kp_ + 16 * TD);                      \
    KD[3] = *(const short8*)(Kp_ + 16 * TD + 32);                 \
    KD[4] = *(const short8*)(Kp_ + 32 * TD);                      \
    KD[5] = *(const short8*)(Kp_ + 32 * TD + 32);                 \
    KD[6] = *(const short8*)(Kp_ + 48 * TD);                      \
    KD[7] = *(const short8*)(Kp_ + 48 * TD + 32);                 \
    VD[0] = *(const short8*)(Vp_);                                \
    VD[1] = *(const short8*)(Vp_ + 16 * 1024);                    \
    VD[2] = *(const short8*)(Vp_ + 32 * 1024);                    \
    VD[3] = *(const short8*)(Vp_ + 48 * 1024);                    \
    VD[4] = *(const short8*)(Vp_ + 32);                           \
    VD[5] = *(const short8*)(Vp_ + 16 * 1024 + 32);               \
    VD[6] = *(const short8*)(Vp_ + 32 * 1024 + 32);               \
    VD[7] = *(const short8*)(Vp_ + 48 * 1024 + 32);               \
  }

#define ATT_TILE(tcur, KC, VC)                                               \
  {                                                                          \
    f32x4 s0 = z, s1 = z, s2 = z, s3 = z;                                    \
    s0 = __builtin_amdgcn_mfma_f32_16x16x32_bf16(qf0, KC[0], s0, 0, 0, 0);   \
    s0 = __builtin_amdgcn_mfma_f32_16x16x32_bf16(qf1, KC[1], s0, 0, 0, 0);   \
    s1 = __builtin_amdgcn_mfma_f32_16x16x32_bf16(qf0, KC[2], s1, 0, 0, 0);   \
    s1 = __builtin_amdgcn_mfma_f32_16x16x32_bf16(qf1, KC[3], s1, 0, 0, 0);   \
    s2 = __builtin_amdgcn_mfma_f32_16x16x32_bf16(qf0, KC[4], s2, 0, 0, 0);   \
    s2 = __builtin_amdgcn_mfma_f32_16x16x32_bf16(qf1, KC[5], s2, 0, 0, 0);   \
    s3 = __builtin_amdgcn_mfma_f32_16x16x32_bf16(qf0, KC[6], s3, 0, 0, 0);   \
    s3 = __builtin_amdgcn_mfma_f32_16x16x32_bf16(qf1, KC[7], s3, 0, 0, 0);   \
    _Pragma("unroll") for (int i = 0; i < 4; ++i) {                          \
      float v0 = s0[i] * 0.125f, v1 = s1[i] * 0.125f;                        \
      float v2 = s2[i] * 0.125f, v3 = s3[i] * 0.125f;                        \
      if (CAUSAL && (tcur) == qt) {                                          \
        int qrow = (w << 4) + (kg << 2) + i;                                 \
        if (r15 > qrow) v0 += MASKV;                                         \
        if (16 + r15 > qrow) v1 += MASKV;                                    \
        if (32 + r15 > qrow) v2 += MASKV;                                    \
        if (48 + r15 > qrow) v3 += MASKV;                                    \
      }                                                                      \
      float p0 = __expf(v0), p1 = __expf(v1);                                \
      float p2 = __expf(v2), p3 = __expf(v3);                                \
      lrow[i] += (p0 + p1) + (p2 + p3);                                      \
      int row = (kg << 2) + i;                                               \
      P_lds[w][row][r15] = f2bf(p0);                                         \
      P_lds[w][row][16 + r15] = f2bf(p1);                                    \
      P_lds[w][row][32 + r15] = f2bf(p2);                                    \
      P_lds[w][row][48 + r15] = f2bf(p3);                                    \
    }                                                                        \
    short8 pf = *(const short8*)&P_lds[w][r15][kg * 8];                      \
    short8 pg = *(const short8*)&P_lds[w][r15][32 + kg * 8];                 \
    o0 = __builtin_amdgcn_mfma_f32_16x16x32_bf16(pf, VC[0], o0, 0, 0, 0);    \
    o1 = __builtin_amdgcn_mfma_f32_16x16x32_bf16(pf, VC[1], o1, 0, 0, 0);    \
    o2 = __builtin_amdgcn_mfma_f32_16x16x32_bf16(pf, VC[2], o2, 0, 0, 0);    \
    o3 = __builtin_amdgcn_mfma_f32_16x16x32_bf16(pf, VC[3], o3, 0, 0, 0);    \
    o0 = __builtin_amdgcn_mfma_f32_16x16x32_bf16(pg, VC[4], o0, 0, 0, 0);    \
    o1 = __builtin_amdgcn_mfma_f32_16x16x32_bf16(pg, VC[5], o1, 0, 0, 0);    \
    o2 = __builtin_amdgcn_mfma_f32_16x16x32_bf16(pg, VC[6], o2, 0, 0, 0);    \
    o3 = __builtin_amdgcn_mfma_f32_16x16x32_bf16(pg, VC[7], o3, 0, 0, 0);    \
  }

  LOADKV(0, kA, vA)
  int t = 0;
  while (true) {
    int tn = t + 1; if (tn >= nkt) tn = nkt - 1;
    LOADKV(tn, kB, vB)
    ATT_TILE(t, kA, vA)
    if (++t >= nkt) break;
    tn = t + 1; if (tn >= nkt) tn = nkt - 1;
    LOADKV(tn, kA, vA)
    ATT_TILE(t, kB, vB)
    if (++t >= nkt) break;
  }
#undef LOADKV
#undef ATT_TILE

#pragma unroll
  for (int i = 0; i < 4; ++i) {
    float rs = lrow[i];
    rs += __shfl_xor(rs, 1, 16);
    rs += __shfl_xor(rs, 2, 16);
    rs += __shfl_xor(rs, 4, 16);
    rs += __shfl_xor(rs, 8, 16);
    float inv = 1.0f / rs;
    size_t base = ((size_t)(b * TS + q0 + w * 16 + (kg << 2) + i)) * TD + h * TDK + r15;
    O[base] = f2bf(o0[i] * inv);
    O[base + 16] = f2bf(o1[i] * inv);
    O[base + 32] = f2bf(o2[i] * inv);
    O[base + 48] = f2bf(o3[i] * inv);
  }
}

// ---------------------------------------------------------------- LayerNorm(x+r)
__global__ __launch_bounds__(256) void ln_k(
    const float* __restrict__ X, const float* __restrict__ R,
    const float* __restrict__ g, const float* __restrict__ be,
    float* __restrict__ out, ushort* __restrict__ outh) {
  __shared__ float red1[4], red2[4];
  const int row = blockIdx.x, tid = threadIdx.x;
  const size_t base = (size_t)row * TD + (tid << 1);
  float2 x2 = *(const float2*)(X + base);
  float2 r2 = *(const float2*)(R + base);
  float a = x2.x + r2.x, c = x2.y + r2.y;
  float s = wave_sum(a + c);
  const int w = tid >> 6;
  if ((tid & 63) == 0) red1[w] = s;
  __syncthreads();
  float mu = (red1[0] + red1[1] + red1[2] + red1[3]) * (1.0f / 512.0f);
  float da = a - mu, dc = c - mu;
  float q = wave_sum(da * da + dc * dc);
  if ((tid & 63) == 0) red2[w] = q;
  __syncthreads();
  float var = (red2[0] + red2[1] + red2[2] + red2[3]) * (1.0f / 512.0f);
  float rstd = rsqrtf(var + 1e-5f);
  int d = tid << 1;
  float2 o;
  o.x = da * rstd * g[d] + be[d];
  o.y = dc * rstd * g[d + 1] + be[d + 1];
  *(float2*)(out + base) = o;
  ushort2 oh; oh.x = f2bf(o.x); oh.y = f2bf(o.y);
  *(ushort2*)(outh + base) = oh;
}

// ---------------------------------------------------------------- final fold
__global__ __launch_bounds__(64) void wbar_k(
    const float* __restrict__ fw, const float* __restrict__ fb,
    float* __restrict__ wb) {
  int d = blockIdx.x, lane = threadIdx.x;
  float s = 0.f;
  if (d < TD) {
#pragma unroll
    for (int r = 0; r < 8; ++r) s += fw[(size_t)d * TD + lane + (r << 6)];
    s = wave_sum(s);
    if (lane == 0) wb[d] = s * (1.0f / 512.0f);
  } else {
#pragma unroll
    for (int r = 0; r < 8; ++r) s += fb[lane + (r << 6)];
    s = wave_sum(s);
    if (lane == 0) wb[TD] = s * (1.0f / 512.0f);
  }
}

__global__ __launch_bounds__(64) void final_k(
    const float* __restrict__ x, const float* __restrict__ wb,
    float* __restrict__ out) {
  int row = blockIdx.x, lane = threadIdx.x;
  float s = 0.f;
#pragma unroll
  for (int r = 0; r < 8; ++r) {
    int d = lane + (r << 6);
    s = fmaf(x[(size_t)row * TD + d], wb[d], s);
  }
  s = wave_sum(s);
  if (lane == 0) out[row] = s + wb[TD];
}

// ---------------------------------------------------------------- launch
extern "C" void kernel_launch(void* const* d_in, const int* in_sizes, int n_in,
                              void* d_out, int out_size, void* d_ws, size_t ws_size,
                              hipStream_t stream) {
  (void)in_sizes; (void)n_in; (void)out_size; (void)ws_size;
  const float* inputs  = (const float*)d_in[0];
  const float* outputs = (const float*)d_in[1];
  const float* eiw = (const float*)d_in[2];
  const float* eib = (const float*)d_in[3];
  const float* eow = (const float*)d_in[4];
  const float* eob = (const float*)d_in[5];
  const float* sa_wq = (const float*)d_in[6];
  const float* sa_bq = (const float*)d_in[7];
  const float* sa_wk = (const float*)d_in[8];
  const float* sa_bk = (const float*)d_in[9];
  const float* sa_wv = (const float*)d_in[10];
  const float* sa_bv = (const float*)d_in[11];
  const float* sa_wo = (const float*)d_in[12];
  const float* sa_bo = (const float*)d_in[13];
  const float* ca_wq = (const float*)d_in[14];
  const float* ca_bq = (const float*)d_in[15];
  const float* ca_wk = (const float*)d_in[16];
  const float* ca_bk = (const float*)d_in[17];
  const float* ca_wv = (const float*)d_in[18];
  const float* ca_bv = (const float*)d_in[19];
  const float* ca_wo = (const float*)d_in[20];
  const float* ca_bo = (const float*)d_in[21];
  const float* ln_g = (const float*)d_in[22];
  const float* ln_b = (const float*)d_in[23];
  const float* ff_w1 = (const float*)d_in[24];
  const float* ff_b1 = (const float*)d_in[25];
  const float* ff_w2 = (const float*)d_in[26];
  const float* ff_b2 = (const float*)d_in[27];
  const float* fin_w = (const float*)d_in[28];
  const float* fin_b = (const float*)d_in[29];

  float* ws = (float*)d_ws;
  const size_t MM = (size_t)TB * TS * TD;  // 2,097,152
  float* bufA = ws;
  float* bufB = ws + MM;
  float* tb   = ws + 2 * MM;
  ushort* u16b = (ushort*)(ws + 3 * MM);
  ushort* ench = u16b;
  ushort* resh = u16b + MM;
  ushort* qbh  = u16b + 2 * MM;
  ushort* kbh  = u16b + 3 * MM;
  ushort* Vth  = u16b + 4 * MM;
  ushort* Wth  = u16b + 5 * MM;
  float* wb    = ws + 7 * MM + MM / 2;
  ushort* hbh1 = qbh;

  embed_k<<<dim3(TS * TD / 256), 256, 0, stream>>>(inputs, outputs, eiw, eib, eow, eob,
                                                   ench, bufA, resh);

  const dim3 gqkv(24, TB * TS / 64);
  const dim3 gp(8, TB * TS / 64);
  const dim3 gf1(32, TB * TS / 64);
  const dim3 gattn(TS / 64, TB * TH);
  const size_t OWQ = 0, OWO = 786432;
  const size_t OCQ = 1048576, OCO = 1835008;
  const size_t OF1 = 2097152, OF2 = 3145728;
  const int KBIG = 1 << 30;

  float* cur = bufA;
  float* alt = bufB;
  for (int lyr = 0; lyr < TNL; ++lyr) {
    const size_t w_off = (size_t)lyr * TD * TD;
    const size_t b_off = (size_t)lyr * TD;
    ushort* hbh2 = (ushort*)alt;
    tcast_k<<<dim3(4096), 256, 0, stream>>>(
        sa_wq + w_off, sa_wk + w_off, sa_wv + w_off, sa_wo + w_off,
        ca_wq + w_off, ca_wk + w_off, ca_wv + w_off, ca_wo + w_off,
        ff_w1 + (size_t)lyr * TD * TDFF, ff_w2 + (size_t)lyr * TDFF * TD, Wth);
    // --- masked self-attention ---
    bgemm_k<5, 0><<<gqkv, 256, 0, stream>>>(
        resh, resh, Wth + OWQ, sa_bq + b_off, sa_bk + b_off, sa_bv + b_off,
        nullptr, qbh, kbh, Vth, 1536, 512, 512, 512, KBIG);
    mattn_k<true><<<gattn, 256, 0, stream>>>(qbh, kbh, Vth, resh);
    bgemm_k<0, 0><<<gp, 256, 0, stream>>>(
        resh, resh, Wth + OWO, sa_bo + b_off, nullptr, nullptr,
        tb, nullptr, nullptr, nullptr, 512, 512, 512, 512, KBIG);
    ln_k<<<dim3(TB * TS), 256, 0, stream>>>(cur, tb, ln_g + b_off, ln_b + b_off, alt, resh);
    // --- cross-attention ---
    bgemm_k<5, 1><<<gqkv, 256, 0, stream>>>(
        resh, ench, Wth + OCQ, ca_bq + b_off, ca_bk + b_off, ca_bv + b_off,
        nullptr, qbh, kbh, Vth, 1536, 512, 512, 512, KBIG);
    mattn_k<false><<<gattn, 256, 0, stream>>>(qbh, kbh, Vth, resh);
    bgemm_k<0, 0><<<gp, 256, 0, stream>>>(
        resh, resh, Wth + OCO, ca_bo + b_off, nullptr, nullptr,
        tb, nullptr, nullptr, nullptr, 512, 512, 512, 512, KBIG);
    ln_k<<<dim3(TB * TS), 256, 0, stream>>>(alt, tb, ln_g + b_off, ln_b + b_off, cur, resh);
    // --- FFN ---
    bgemm_k<7, 0><<<gf1, 256, 0, stream>>>(
        resh, resh, Wth + OF1, ff_b1 + (size_t)lyr * TDFF, nullptr, nullptr,
        nullptr, hbh1, hbh2, nullptr, 2048, 512, 512, 512, KBIG);
    bgemm_k<0, 2><<<gp, 256, 0, stream>>>(
        hbh1, hbh2, Wth + OF2, ff_b2 + b_off, nullptr, nullptr,
        tb, nullptr, nullptr, nullptr, 512, 2048, 1024, 2048, 1024);
    ln_k<<<dim3(TB * TS), 256, 0, stream>>>(cur, tb, ln_g + b_off, ln_b + b_off, alt, resh);
    float* t2 = cur; cur = alt; alt = t2;
  }
  wbar_k<<<dim3(TD + 1), 64, 0, stream>>>(fin_w, fin_b, wb);
  final_k<<<dim3(TB * TS), 64, 0, stream>>>(cur, wb, (float*)d_out);
}